// Round 12
// baseline (355.166 us; speedup 1.0000x reference)
//
#include <hip/hip_runtime.h>

#define IN_F 4096
#define OUT_F 4096
#define NROWS 8192   // 4*2048
#define BK 32
#define NT (IN_F / BK)   // 128

typedef __attribute__((ext_vector_type(4))) float f32x4;
typedef __attribute__((ext_vector_type(16))) float f32x16;
typedef __attribute__((ext_vector_type(8))) short bf16x8;
typedef __attribute__((ext_vector_type(8))) unsigned short u16x8;

__device__ __forceinline__ unsigned short f2bf(float f) {
  union { float f; unsigned u; } x; x.f = f;
  unsigned r = x.u + 0x7FFFu + ((x.u >> 16) & 1u);   // RNE
  return (unsigned short)(r >> 16);
}

__device__ __forceinline__ void gload_lds16(const unsigned short* g, unsigned short* l) {
  __builtin_amdgcn_global_load_lds((__attribute__((address_space(1))) void*)g,
                                   (__attribute__((address_space(3))) void*)l,
                                   16, 0, 0);
}

// in-register 16-point FWHT (4 butterfly bits)
__device__ __forceinline__ void bfly16(float v[16]) {
#pragma unroll
  for (int s = 1; s < 16; s <<= 1) {
#pragma unroll
    for (int i = 0; i < 16; ++i) {
      if (!(i & s)) { float a = v[i], b = v[i + s]; v[i] = a + b; v[i + s] = a - b; }
    }
  }
}

// ---------------- 1) dequant ----------------
__global__ __launch_bounds__(256) void dequant_kernel(const int* __restrict__ Q,
                                                      const float* __restrict__ grid,
                                                      unsigned short* __restrict__ Wb) {
  int g = blockIdx.x * 256 + threadIdx.x;
  int idx = Q[g];
  const f32x4* gp = (const f32x4*)(grid + idx * 8);
  f32x4 v0 = gp[0], v1 = gp[1];
  u16x8 o;
  o[0] = f2bf(v0[0]); o[1] = f2bf(v0[1]); o[2] = f2bf(v0[2]); o[3] = f2bf(v0[3]);
  o[4] = f2bf(v1[0]); o[5] = f2bf(v1[1]); o[6] = f2bf(v1[2]); o[7] = f2bf(v1[3]);
  *(u16x8*)(Wb + (size_t)g * 8) = o;
}

// ---------------- 2) fwht1: H = fwht(x*SU) -> bf16 ----------------
__global__ __launch_bounds__(256) void fwht1_kernel(const float* __restrict__ x,
                                                    const float* __restrict__ SU,
                                                    unsigned short* __restrict__ Hb) {
  __shared__ float buf[4096];
  int tid = threadIdx.x;
  size_t rbase = (size_t)blockIdx.x * IN_F;
  const f32x4* x4 = (const f32x4*)(x + rbase);
  const f32x4* su4 = (const f32x4*)SU;
  f32x4* b4 = (f32x4*)buf;
#pragma unroll
  for (int s = 0; s < 4; ++s) {
    int c = tid + 256 * s;
    f32x4 v = x4[c];
    f32x4 u = su4[c];
    v.x *= u.x; v.y *= u.y; v.z *= u.z; v.w *= u.w;
    b4[c] = v;
  }
  __syncthreads();
  float v[16];
  {
#pragma unroll
    for (int j = 0; j < 4; ++j) {
      f32x4 t4 = b4[tid * 4 + j];
      v[j*4+0] = t4.x; v[j*4+1] = t4.y; v[j*4+2] = t4.z; v[j*4+3] = t4.w;
    }
    bfly16(v);
#pragma unroll
    for (int j = 0; j < 4; ++j) {
      f32x4 t4; t4.x = v[j*4+0]; t4.y = v[j*4+1]; t4.z = v[j*4+2]; t4.w = v[j*4+3];
      b4[tid * 4 + j] = t4;
    }
  }
  __syncthreads();
  {
    int lo = tid & 15, hi = tid >> 4;
    int base = lo + (hi << 8);
#pragma unroll
    for (int j = 0; j < 16; ++j) v[j] = buf[base + (j << 4)];
    bfly16(v);
#pragma unroll
    for (int j = 0; j < 16; ++j) buf[base + (j << 4)] = v[j];
  }
  __syncthreads();
  {
#pragma unroll
    for (int j = 0; j < 16; ++j) v[j] = buf[tid + (j << 8)];
    bfly16(v);
#pragma unroll
    for (int j = 0; j < 16; ++j)
      Hb[rbase + tid + (j << 8)] = f2bf(v[j] * 0.015625f);   // 1/sqrt(4096)
  }
}

// ---------------- 3) GEMM 256x256, 4 waves x (128x128), 32x32x16 MFMA, ring-4 LDS ----------------
// Per-wave 128x128 halves LDS reads/MFMA (16 reads / 32 MFMA); 1 wave/SIMD.
// 32x32x16 (32.3 cy pipe) amortizes the single-wave inter-MFMA gap that made
// r7's 16x16 land at exactly 2.0x floor.  acc (256 regs) pinned to AGPR via
// "+a" (r7-proven, no spill at __launch_bounds__(256,1): 512-reg unified budget).
__global__ __launch_bounds__(256, 1) void gemm256_kernel(const unsigned short* __restrict__ Hb,
                                                         const unsigned short* __restrict__ Wb,
                                                         float* __restrict__ Y) {
  __shared__ unsigned short lds[4][2][256 * BK];   // 4 slots x (A,B) x 16KB = 128 KiB
  const int tid = threadIdx.x;
  const int lane = tid & 63;
  const int wid = tid >> 6;        // 0..3
  const int wr = wid >> 1;         // 0..1  (M half)
  const int wc = wid & 1;          // 0..1  (N half)
  const int l31 = lane & 31;
  const int hi5 = lane >> 5;

  const int bid = blockIdx.x;
  const int swz = (bid & 7) * 64 + (bid >> 3);     // nwg=512, bijective XCD swizzle
  const int brow = (swz >> 4) << 8;
  const int bcol = (swz & 15) << 8;

  const unsigned short* Ab = Hb + (size_t)brow * IN_F;
  const unsigned short* Bb = Wb + (size_t)bcol * IN_F;

  // staging (r7-identical): 8 gloads/thread (4A+4B), rows r0+{0,64,128,192};
  // bank swizzle on GLOBAL source; LDS dest lane-linear (gload requirement).
  const int r0 = tid >> 2;
  const int sc = ((tid & 3) ^ ((r0 >> 1) & 3)) << 3;
  const unsigned short* Ag0 = Ab + (size_t)(r0 +   0) * IN_F + sc;
  const unsigned short* Ag1 = Ab + (size_t)(r0 +  64) * IN_F + sc;
  const unsigned short* Ag2 = Ab + (size_t)(r0 + 128) * IN_F + sc;
  const unsigned short* Ag3 = Ab + (size_t)(r0 + 192) * IN_F + sc;
  const unsigned short* Bg0 = Bb + (size_t)(r0 +   0) * IN_F + sc;
  const unsigned short* Bg1 = Bb + (size_t)(r0 +  64) * IN_F + sc;
  const unsigned short* Bg2 = Bb + (size_t)(r0 + 128) * IN_F + sc;
  const unsigned short* Bg3 = Bb + (size_t)(r0 + 192) * IN_F + sc;

#define STAGE(t, s) { \
  gload_lds16(Ag0 + (t) * BK, &lds[s][0][tid * 8]); \
  gload_lds16(Ag1 + (t) * BK, &lds[s][0][(tid + 256) * 8]); \
  gload_lds16(Ag2 + (t) * BK, &lds[s][0][(tid + 512) * 8]); \
  gload_lds16(Ag3 + (t) * BK, &lds[s][0][(tid + 768) * 8]); \
  gload_lds16(Bg0 + (t) * BK, &lds[s][1][tid * 8]); \
  gload_lds16(Bg1 + (t) * BK, &lds[s][1][(tid + 256) * 8]); \
  gload_lds16(Bg2 + (t) * BK, &lds[s][1][(tid + 512) * 8]); \
  gload_lds16(Bg3 + (t) * BK, &lds[s][1][(tid + 768) * 8]); }

  // 32x32x16 operand read: lane holds [Rblk + (lane&31)][k = kk*16 + (lane>>5)*8 + j]
  // slot-swizzle ^((row>>1)&3) matches the staged layout (balanced: 8 words/bank).
  auto fr32 = [&](const unsigned short* base, int Rblk, int kk) -> bf16x8 {
    int row = Rblk + l31;
    int slot = ((kk << 1) + hi5) ^ ((row >> 1) & 3);
    return *(const bf16x8*)(base + row * BK + (slot << 3));
  };

  const int ar = wr * 128;
  const int br = wc * 128;

  // sets indexed [mOrN*2 + kk]
#define READ_A(t, aS) { const unsigned short* As_ = &lds[(t) & 3][0][0]; \
  aS[0] = fr32(As_, ar +  0, 0); aS[1] = fr32(As_, ar +  0, 1); \
  aS[2] = fr32(As_, ar + 32, 0); aS[3] = fr32(As_, ar + 32, 1); \
  aS[4] = fr32(As_, ar + 64, 0); aS[5] = fr32(As_, ar + 64, 1); \
  aS[6] = fr32(As_, ar + 96, 0); aS[7] = fr32(As_, ar + 96, 1); }
#define READ_B(t, bS) { const unsigned short* Bs_ = &lds[(t) & 3][1][0]; \
  bS[0] = fr32(Bs_, br +  0, 0); bS[1] = fr32(Bs_, br +  0, 1); \
  bS[2] = fr32(Bs_, br + 32, 0); bS[3] = fr32(Bs_, br + 32, 1); \
  bS[4] = fr32(Bs_, br + 64, 0); bS[5] = fr32(Bs_, br + 64, 1); \
  bS[6] = fr32(Bs_, br + 96, 0); bS[7] = fr32(Bs_, br + 96, 1); }

  // acc[m*4+n] (f32x16, AGPR-pinned)
#define MM(f, A, B) asm volatile("v_mfma_f32_32x32x16_bf16 %0, %1, %2, %0" \
                                 : "+a"(acc[f]) : "v"(A), "v"(B))
  // one M-row of the quadrant grid at kstep kk: 4 MFMA
#define MMR(m, kk, aS, bS) { \
  MM((m)*4+0, aS[(m)*2+(kk)], bS[0*2+(kk)]); \
  MM((m)*4+1, aS[(m)*2+(kk)], bS[1*2+(kk)]); \
  MM((m)*4+2, aS[(m)*2+(kk)], bS[2*2+(kk)]); \
  MM((m)*4+3, aS[(m)*2+(kk)], bS[3*2+(kk)]); }

#define TILE_BODY(t, aC_, bC_, aN_, bN_) { \
  if ((t) + 2 < NT) { asm volatile("s_waitcnt vmcnt(8)" ::: "memory"); } \
  else              { asm volatile("s_waitcnt vmcnt(0)" ::: "memory"); } \
  __builtin_amdgcn_s_barrier(); \
  if ((t) + 3 < NT) STAGE((t) + 3, ((t) + 3) & 3); \
  asm volatile("s_waitcnt lgkmcnt(0)" ::: "memory"); \
  __builtin_amdgcn_sched_barrier(0); \
  __builtin_amdgcn_s_setprio(1); \
  MMR(0, 0, aC_, bC_); MMR(1, 0, aC_, bC_); MMR(2, 0, aC_, bC_); \
  __builtin_amdgcn_s_setprio(0); \
  if ((t) + 1 < NT) READ_A((t) + 1, aN_); \
  __builtin_amdgcn_sched_barrier(0); \
  __builtin_amdgcn_s_setprio(1); \
  MMR(3, 0, aC_, bC_); MMR(0, 1, aC_, bC_); \
  __builtin_amdgcn_s_setprio(0); \
  if ((t) + 1 < NT) READ_B((t) + 1, bN_); \
  __builtin_amdgcn_sched_barrier(0); \
  __builtin_amdgcn_s_setprio(1); \
  MMR(1, 1, aC_, bC_); MMR(2, 1, aC_, bC_); MMR(3, 1, aC_, bC_); \
  __builtin_amdgcn_s_setprio(0); }

  f32x16 acc[16] = {};   // 256 AGPR
  bf16x8 aC[8], bC[8], aN[8], bN[8];

  // prologue: stage tiles 0,1,2 (24 loads); tile0 resident after vmcnt(16)
  STAGE(0, 0); STAGE(1, 1); STAGE(2, 2);
  asm volatile("s_waitcnt vmcnt(16)" ::: "memory");
  __builtin_amdgcn_s_barrier();
  READ_A(0, aC); READ_B(0, bC);

  for (int t = 0; t < NT; t += 2) {
    TILE_BODY(t,     aC, bC, aN, bN);
    TILE_BODY(t + 1, aN, bN, aC, bC);
  }

  // epilogue: 32x32 C/D layout (m74/m101): col = lane&31, row = (r&3)+8*(r>>2)+4*(lane>>5)
#pragma unroll
  for (int mi = 0; mi < 4; ++mi)
#pragma unroll
    for (int ni = 0; ni < 4; ++ni) {
      int f = mi * 4 + ni;
      int gr = brow + wr * 128 + mi * 32 + 4 * hi5;
      float* yp = Y + (size_t)gr * OUT_F + bcol + wc * 128 + ni * 32 + l31;
#pragma unroll
      for (int r = 0; r < 16; ++r) {
        int rr = (r & 3) + 8 * (r >> 2);
        yp[(size_t)rr * OUT_F] = acc[f][r];
      }
    }
#undef STAGE
#undef READ_A
#undef READ_B
#undef MM
#undef MMR
#undef TILE_BODY
}

// ---------------- 4) fwht2 (in-place on d_out) + SV + bias ----------------
__global__ __launch_bounds__(256) void fwht2_kernel(float* __restrict__ Y,
                                                    const float* __restrict__ SV,
                                                    const float* __restrict__ bias) {
  __shared__ float buf[4096];
  int tid = threadIdx.x;
  size_t rbase = (size_t)blockIdx.x * OUT_F;
  f32x4* y4 = (f32x4*)(Y + rbase);
  f32x4* b4 = (f32x4*)buf;
#pragma unroll
  for (int s = 0; s < 4; ++s) {
    int c = tid + 256 * s;
    b4[c] = y4[c];
  }
  __syncthreads();
  float v[16];
  {
#pragma unroll
    for (int j = 0; j < 4; ++j) {
      f32x4 t4 = b4[tid * 4 + j];
      v[j*4+0] = t4.x; v[j*4+1] = t4.y; v[j*4+2] = t4.z; v[j*4+3] = t4.w;
    }
    bfly16(v);
#pragma unroll
    for (int j = 0; j < 4; ++j) {
      f32x4 t4; t4.x = v[j*4+0]; t4.y = v[j*4+1]; t4.z = v[j*4+2]; t4.w = v[j*4+3];
      b4[tid * 4 + j] = t4;
    }
  }
  __syncthreads();
  {
    int lo = tid & 15, hi = tid >> 4;
    int base = lo + (hi << 8);
#pragma unroll
    for (int j = 0; j < 16; ++j) v[j] = buf[base + (j << 4)];
    bfly16(v);
#pragma unroll
    for (int j = 0; j < 16; ++j) buf[base + (j << 4)] = v[j];
  }
  __syncthreads();
  {
#pragma unroll
    for (int j = 0; j < 16; ++j) v[j] = buf[tid + (j << 8)];
    bfly16(v);
#pragma unroll
    for (int j = 0; j < 16; ++j) {
      int col = tid + (j << 8);
      Y[rbase + col] = v[j] * 0.015625f * SV[col] + bias[col];
    }
  }
}

extern "C" void kernel_launch(void* const* d_in, const int* in_sizes, int n_in,
                              void* d_out, int out_size, void* d_ws, size_t ws_size,
                              hipStream_t stream) {
  const float* x     = (const float*)d_in[0];
  const int*   Qidxs = (const int*)d_in[1];
  const float* grid  = (const float*)d_in[2];
  const float* SU    = (const float*)d_in[3];
  const float* SV    = (const float*)d_in[4];
  const float* bias  = (const float*)d_in[5];
  float* out = (float*)d_out;

  unsigned short* Wb = (unsigned short*)d_ws;                    // 4096*4096 bf16 = 33.5 MB
  unsigned short* Hb = Wb + (size_t)OUT_F * IN_F;                // 8192*4096 bf16 = 67 MB

  hipLaunchKernelGGL(dequant_kernel, dim3((OUT_F * (IN_F / 8)) / 256), dim3(256), 0, stream,
                     Qidxs, grid, Wb);
  hipLaunchKernelGGL(fwht1_kernel, dim3(NROWS), dim3(256), 0, stream, x, SU, Hb);
  hipLaunchKernelGGL(gemm256_kernel, dim3((NROWS / 256) * (OUT_F / 256)), dim3(256), 0, stream,
                     Hb, Wb, out);
  hipLaunchKernelGGL(fwht2_kernel, dim3(NROWS), dim3(256), 0, stream, out, SV, bias);
}

// Round 13
// 330.784 us; speedup vs baseline: 1.0737x; 1.0737x over previous
//
#include <hip/hip_runtime.h>

#define IN_F 4096
#define OUT_F 4096
#define NROWS 8192   // 4*2048
#define BK 32
#define NT (IN_F / BK)   // 128

typedef __attribute__((ext_vector_type(4))) float f32x4;
typedef __attribute__((ext_vector_type(8))) short bf16x8;
typedef __attribute__((ext_vector_type(8))) unsigned short u16x8;

__device__ __forceinline__ unsigned short f2bf(float f) {
  union { float f; unsigned u; } x; x.f = f;
  unsigned r = x.u + 0x7FFFu + ((x.u >> 16) & 1u);   // RNE
  return (unsigned short)(r >> 16);
}

__device__ __forceinline__ void gload_lds16(const unsigned short* g, unsigned short* l) {
  __builtin_amdgcn_global_load_lds((__attribute__((address_space(1))) void*)g,
                                   (__attribute__((address_space(3))) void*)l,
                                   16, 0, 0);
}

// in-register 16-point FWHT (4 butterfly bits)
__device__ __forceinline__ void bfly16(float v[16]) {
#pragma unroll
  for (int s = 1; s < 16; s <<= 1) {
#pragma unroll
    for (int i = 0; i < 16; ++i) {
      if (!(i & s)) { float a = v[i], b = v[i + s]; v[i] = a + b; v[i + s] = a - b; }
    }
  }
}

// ---------------- 1) dequant ----------------
__global__ __launch_bounds__(256) void dequant_kernel(const int* __restrict__ Q,
                                                      const float* __restrict__ grid,
                                                      unsigned short* __restrict__ Wb) {
  int g = blockIdx.x * 256 + threadIdx.x;
  int idx = Q[g];
  const f32x4* gp = (const f32x4*)(grid + idx * 8);
  f32x4 v0 = gp[0], v1 = gp[1];
  u16x8 o;
  o[0] = f2bf(v0[0]); o[1] = f2bf(v0[1]); o[2] = f2bf(v0[2]); o[3] = f2bf(v0[3]);
  o[4] = f2bf(v1[0]); o[5] = f2bf(v1[1]); o[6] = f2bf(v1[2]); o[7] = f2bf(v1[3]);
  *(u16x8*)(Wb + (size_t)g * 8) = o;
}

// ---------------- 2) fwht1: H = fwht(x*SU) -> bf16 ----------------
__global__ __launch_bounds__(256) void fwht1_kernel(const float* __restrict__ x,
                                                    const float* __restrict__ SU,
                                                    unsigned short* __restrict__ Hb) {
  __shared__ float buf[4096];
  int tid = threadIdx.x;
  size_t rbase = (size_t)blockIdx.x * IN_F;
  const f32x4* x4 = (const f32x4*)(x + rbase);
  const f32x4* su4 = (const f32x4*)SU;
  f32x4* b4 = (f32x4*)buf;
#pragma unroll
  for (int s = 0; s < 4; ++s) {
    int c = tid + 256 * s;
    f32x4 v = x4[c];
    f32x4 u = su4[c];
    v.x *= u.x; v.y *= u.y; v.z *= u.z; v.w *= u.w;
    b4[c] = v;
  }
  __syncthreads();
  float v[16];
  {
#pragma unroll
    for (int j = 0; j < 4; ++j) {
      f32x4 t4 = b4[tid * 4 + j];
      v[j*4+0] = t4.x; v[j*4+1] = t4.y; v[j*4+2] = t4.z; v[j*4+3] = t4.w;
    }
    bfly16(v);
#pragma unroll
    for (int j = 0; j < 4; ++j) {
      f32x4 t4; t4.x = v[j*4+0]; t4.y = v[j*4+1]; t4.z = v[j*4+2]; t4.w = v[j*4+3];
      b4[tid * 4 + j] = t4;
    }
  }
  __syncthreads();
  {
    int lo = tid & 15, hi = tid >> 4;
    int base = lo + (hi << 8);
#pragma unroll
    for (int j = 0; j < 16; ++j) v[j] = buf[base + (j << 4)];
    bfly16(v);
#pragma unroll
    for (int j = 0; j < 16; ++j) buf[base + (j << 4)] = v[j];
  }
  __syncthreads();
  {
#pragma unroll
    for (int j = 0; j < 16; ++j) v[j] = buf[tid + (j << 8)];
    bfly16(v);
#pragma unroll
    for (int j = 0; j < 16; ++j)
      Hb[rbase + tid + (j << 8)] = f2bf(v[j] * 0.015625f);   // 1/sqrt(4096)
  }
}

// ---------------- 3) GEMM 256x256, 8 waves x (128x64), BK=32, ring-4 ----------------
// Anti-lockstep schedule: next-tile A-frag ds_reads issue BETWEEN MFMA bursts
// (LDS pipe drains while matrix pipe busy); B-frags (4 reads) at body top.
// One barrier/tile; counted vmcnt(4); A-frag reg double-buffer; intrinsic MFMA
// (acc -> AGPR automatically, r9-proven no-spill).
__global__ __launch_bounds__(512) void gemm256_kernel(const unsigned short* __restrict__ Hb,
                                                      const unsigned short* __restrict__ Wb,
                                                      float* __restrict__ Y) {
  __shared__ unsigned short lds[4][2][256 * BK];   // ring-4 x (A,B) x 16KB = 128 KiB
  const int tid = threadIdx.x;
  const int lane = tid & 63;
  const int wid = tid >> 6;        // 0..7
  const int wr = wid >> 2;         // 0..1  (M half)
  const int wc = wid & 3;          // 0..3  (N quarter)
  const int lrow = lane & 15;
  const int kgrp = lane >> 4;

  const int bid = blockIdx.x;
  const int swz = (bid & 7) * 64 + (bid >> 3);     // nwg=512, bijective XCD swizzle
  const int brow = (swz >> 4) << 8;
  const int bcol = (swz & 15) << 8;

  // staging: 4 gloads/thread/tile (2A+2B; rows r0, r0+128); bank swizzle on the
  // GLOBAL source (r3-verified 0-conflict); LDS dest lane-linear (gload req).
  const int r0 = tid >> 2;
  const int sc = ((tid & 3) ^ ((r0 >> 1) & 3)) << 3;
  const unsigned short* AgR0 = Hb + (size_t)(brow + r0) * IN_F + sc;
  const unsigned short* AgR1 = Hb + (size_t)(brow + r0 + 128) * IN_F + sc;
  const unsigned short* BgR0 = Wb + (size_t)(bcol + r0) * IN_F + sc;
  const unsigned short* BgR1 = Wb + (size_t)(bcol + r0 + 128) * IN_F + sc;

#define STAGE(t) { \
  gload_lds16(AgR0 + (t) * BK, &lds[(t) & 3][0][tid * 8]); \
  gload_lds16(AgR1 + (t) * BK, &lds[(t) & 3][0][(tid + 512) * 8]); \
  gload_lds16(BgR0 + (t) * BK, &lds[(t) & 3][1][tid * 8]); \
  gload_lds16(BgR1 + (t) * BK, &lds[(t) & 3][1][(tid + 512) * 8]); }

  auto fragLd = [&](const unsigned short* base, int R) -> bf16x8 {
    return *(const bf16x8*)(base + R * BK + ((kgrp ^ ((R >> 1) & 3)) << 3));
  };

  const int ar = wr * 128 + lrow;
  const int br = wc * 64 + lrow;

#define READ_A(t, aS) { const unsigned short* As_ = &lds[(t) & 3][0][0]; \
  aS[0] = fragLd(As_, ar +   0); aS[1] = fragLd(As_, ar +  16); \
  aS[2] = fragLd(As_, ar +  32); aS[3] = fragLd(As_, ar +  48); \
  aS[4] = fragLd(As_, ar +  64); aS[5] = fragLd(As_, ar +  80); \
  aS[6] = fragLd(As_, ar +  96); aS[7] = fragLd(As_, ar + 112); }
#define READ_B(t) { const unsigned short* Bs_ = &lds[(t) & 3][1][0]; \
  b0 = fragLd(Bs_, br +  0); b1 = fragLd(Bs_, br + 16); \
  b2 = fragLd(Bs_, br + 32); b3 = fragLd(Bs_, br + 48); }

#define MM(i, A, B) acc[i] = __builtin_amdgcn_mfma_f32_16x16x32_bf16(A, B, acc[i], 0, 0, 0)
#define MMROW(m, aS) { \
  MM((m)*4+0, aS[m], b0); MM((m)*4+1, aS[m], b1); \
  MM((m)*4+2, aS[m], b2); MM((m)*4+3, aS[m], b3); }

  // body t: fragments of tile t already in regs (aCur; b read at top).
  // Next-tile A-reads issue after the first 8 MFMA -> hide under remaining 24.
#define TILE_BODY(t, aCur, aNxt) { \
  if ((t) + 3 <= NT) { asm volatile("s_waitcnt vmcnt(4)" ::: "memory"); } \
  else               { asm volatile("s_waitcnt vmcnt(0)" ::: "memory"); } \
  __builtin_amdgcn_s_barrier(); \
  if ((t) + 3 < NT) STAGE((t) + 3); \
  READ_B(t); \
  asm volatile("s_waitcnt lgkmcnt(0)" ::: "memory"); \
  __builtin_amdgcn_sched_barrier(0); \
  __builtin_amdgcn_s_setprio(1); \
  MMROW(0, aCur); MMROW(1, aCur); \
  __builtin_amdgcn_s_setprio(0); \
  if ((t) + 1 < NT) READ_A((t) + 1, aNxt); \
  __builtin_amdgcn_sched_barrier(0); \
  __builtin_amdgcn_s_setprio(1); \
  MMROW(2, aCur); MMROW(3, aCur); MMROW(4, aCur); MMROW(5, aCur); \
  MMROW(6, aCur); MMROW(7, aCur); \
  __builtin_amdgcn_s_setprio(0); }

  f32x4 acc[32] = {};
  bf16x8 aC[8], aN[8], b0, b1, b2, b3;

  // prologue: stage tiles 0,1,2 (12 loads); vmcnt(4) retires S0,S1 (slot0+1
  // resident); read tile0 A-frags.
  STAGE(0); STAGE(1); STAGE(2);
  asm volatile("s_waitcnt vmcnt(4)" ::: "memory");
  __builtin_amdgcn_s_barrier();
  READ_A(0, aC);

  for (int t = 0; t < NT; t += 2) {
    TILE_BODY(t,     aC, aN);
    TILE_BODY(t + 1, aN, aC);
  }

  // epilogue: C/D layout col=lane&15 (B side), row=kgrp*4+r (A side)
#pragma unroll
  for (int mf = 0; mf < 8; ++mf) {
    int grow = brow + wr * 128 + mf * 16 + kgrp * 4;
    float* yp = Y + (size_t)grow * OUT_F + bcol + wc * 64 + lrow;
#pragma unroll
    for (int r = 0; r < 4; ++r)
#pragma unroll
      for (int nf = 0; nf < 4; ++nf)
        yp[(size_t)r * OUT_F + nf * 16] = acc[mf * 4 + nf][r];
  }
#undef STAGE
#undef READ_A
#undef READ_B
#undef MM
#undef MMROW
#undef TILE_BODY
}

// ---------------- 4) fwht2 (in-place on d_out) + SV + bias ----------------
__global__ __launch_bounds__(256) void fwht2_kernel(float* __restrict__ Y,
                                                    const float* __restrict__ SV,
                                                    const float* __restrict__ bias) {
  __shared__ float buf[4096];
  int tid = threadIdx.x;
  size_t rbase = (size_t)blockIdx.x * OUT_F;
  f32x4* y4 = (f32x4*)(Y + rbase);
  f32x4* b4 = (f32x4*)buf;
#pragma unroll
  for (int s = 0; s < 4; ++s) {
    int c = tid + 256 * s;
    b4[c] = y4[c];
  }
  __syncthreads();
  float v[16];
  {
#pragma unroll
    for (int j = 0; j < 4; ++j) {
      f32x4 t4 = b4[tid * 4 + j];
      v[j*4+0] = t4.x; v[j*4+1] = t4.y; v[j*4+2] = t4.z; v[j*4+3] = t4.w;
    }
    bfly16(v);
#pragma unroll
    for (int j = 0; j < 4; ++j) {
      f32x4 t4; t4.x = v[j*4+0]; t4.y = v[j*4+1]; t4.z = v[j*4+2]; t4.w = v[j*4+3];
      b4[tid * 4 + j] = t4;
    }
  }
  __syncthreads();
  {
    int lo = tid & 15, hi = tid >> 4;
    int base = lo + (hi << 8);
#pragma unroll
    for (int j = 0; j < 16; ++j) v[j] = buf[base + (j << 4)];
    bfly16(v);
#pragma unroll
    for (int j = 0; j < 16; ++j) buf[base + (j << 4)] = v[j];
  }
  __syncthreads();
  {
#pragma unroll
    for (int j = 0; j < 16; ++j) v[j] = buf[tid + (j << 8)];
    bfly16(v);
#pragma unroll
    for (int j = 0; j < 16; ++j) {
      int col = tid + (j << 8);
      Y[rbase + col] = v[j] * 0.015625f * SV[col] + bias[col];
    }
  }
}

extern "C" void kernel_launch(void* const* d_in, const int* in_sizes, int n_in,
                              void* d_out, int out_size, void* d_ws, size_t ws_size,
                              hipStream_t stream) {
  const float* x     = (const float*)d_in[0];
  const int*   Qidxs = (const int*)d_in[1];
  const float* grid  = (const float*)d_in[2];
  const float* SU    = (const float*)d_in[3];
  const float* SV    = (const float*)d_in[4];
  const float* bias  = (const float*)d_in[5];
  float* out = (float*)d_out;

  unsigned short* Wb = (unsigned short*)d_ws;                    // 4096*4096 bf16 = 33.5 MB
  unsigned short* Hb = Wb + (size_t)OUT_F * IN_F;                // 8192*4096 bf16 = 67 MB

  hipLaunchKernelGGL(dequant_kernel, dim3((OUT_F * (IN_F / 8)) / 256), dim3(256), 0, stream,
                     Qidxs, grid, Wb);
  hipLaunchKernelGGL(fwht1_kernel, dim3(NROWS), dim3(256), 0, stream, x, SU, Hb);
  hipLaunchKernelGGL(gemm256_kernel, dim3((NROWS / 256) * (OUT_F / 256)), dim3(512), 0, stream,
                     Hb, Wb, out);
  hipLaunchKernelGGL(fwht2_kernel, dim3(NROWS), dim3(256), 0, stream, out, SV, bias);
}